// Round 4
// baseline (73.372 us; speedup 1.0000x reference)
//
#include <hip/hip_runtime.h>

// Quanv2d: 4096 images x 196 (2x2) patches -> 4-qubit circuit -> 4 expvals.
// One thread per patch/circuit; 16-amplitude state held in registers.
//
// Circuit folding (mathematically exact):
//   per qubit: H, RY(x_q), RY(w[0,q])          -> product state with phi = x_q + w[0,q]
//   CNOT chain (register permutation, free)
//   RY(w[0,4+q]) . RY(w[1,q])                  -> one RY with phi2 = w[0,4+q] + w[1,q]
//   CNOT chain
//   RY(w[1,4+q])                               -> phi3
//   measure Z_q = sum_i sign * psi_i^2

constexpr float INV_SQRT2f = 0.7071067811865476f;

#define TOTAL_CIRCUITS (4096 * 196)   // 802816 = 3136 * 256

__global__ __launch_bounds__(256) void quanv_kernel(
    const float* __restrict__ x,    // (4096,1,28,28)
    const float* __restrict__ w,    // (2,8) row-major
    float* __restrict__ out)        // (4096,784)
{
    // tw[0:4)=cos(phi2/2), [4:8)=sin(phi2/2), [8:12)=cos(phi3/2), [12:16)=sin(phi3/2), [16:20)=w[0,q]
    __shared__ float tw[20];
    const int tid = threadIdx.x;
    if (tid < 12) {
        const int q = tid & 3;
        if (tid < 8) {
            const float half_ang = (tid < 4) ? 0.5f * (w[4 + q] + w[8 + q])
                                             : 0.5f * w[12 + q];
            float s, c;
            __sincosf(half_ang, &s, &c);
            const int base = (tid < 4) ? 0 : 8;
            tw[base + q]     = c;
            tw[base + 4 + q] = s;
        } else {
            tw[16 + q] = w[q];
        }
    }
    __syncthreads();

    const int t = blockIdx.x * 256 + tid;   // grid is exact: 3136*256 == TOTAL_CIRCUITS
    const int b  = t / 196;
    const int p  = t - b * 196;
    const int pi = p / 14;
    const int pj = p - pi * 14;

    // patch values: angles q=0..3 = x[2i,2j], x[2i,2j+1], x[2i+1,2j], x[2i+1,2j+1]
    const float* xp = x + b * 784 + pi * 56 + pj * 2;
    const float2 r0 = *reinterpret_cast<const float2*>(xp);
    const float2 r1 = *reinterpret_cast<const float2*>(xp + 28);
    const float ang[4] = { r0.x, r0.y, r1.x, r1.y };

    // per-qubit initial 2-vectors: RY(x_q + w0q) . H . |0>
    float v0[4], v1[4];
    #pragma unroll
    for (int q = 0; q < 4; ++q) {
        float s, c;
        __sincosf(0.5f * (ang[q] + tw[16 + q]), &s, &c);
        v0[q] = (c - s) * INV_SQRT2f;
        v1[q] = (c + s) * INV_SQRT2f;
    }

    // psi[i], i = (q0<<3)|(q1<<2)|(q2<<1)|q3  (qubit 0 = MSB, per reference axis order)
    float psi[16];
    {
        float p01[4];
        p01[0] = v0[0] * v0[1]; p01[1] = v0[0] * v1[1];
        p01[2] = v1[0] * v0[1]; p01[3] = v1[0] * v1[1];
        float p012[8];
        #pragma unroll
        for (int i = 0; i < 4; ++i) {
            p012[2 * i]     = p01[i] * v0[2];
            p012[2 * i + 1] = p01[i] * v1[2];
        }
        #pragma unroll
        for (int i = 0; i < 8; ++i) {
            psi[2 * i]     = p012[i] * v0[3];
            psi[2 * i + 1] = p012[i] * v1[3];
        }
    }

    // CNOT(c,t): for indices with control bit set, swap target bit. Free (reg rename).
#define CNOT_GATE(C, T)                                                        \
    {                                                                          \
        const int bc = 1 << (3 - (C)), bt = 1 << (3 - (T));                    \
        _Pragma("unroll")                                                      \
        for (int i = 0; i < 16; ++i)                                           \
            if ((i & bc) && !(i & bt)) {                                       \
                const float tmp = psi[i];                                      \
                psi[i] = psi[i | bt];                                          \
                psi[i | bt] = tmp;                                             \
            }                                                                  \
    }

#define RY_GATE(Q, CC, SS)                                                     \
    {                                                                          \
        const int bq = 1 << (3 - (Q));                                         \
        _Pragma("unroll")                                                      \
        for (int i = 0; i < 16; ++i)                                           \
            if (!(i & bq)) {                                                   \
                const float a0 = psi[i], a1 = psi[i | bq];                     \
                psi[i]      = (CC) * a0 - (SS) * a1;                           \
                psi[i | bq] = (SS) * a0 + (CC) * a1;                           \
            }                                                                  \
    }

    // depth 0 entangler
    CNOT_GATE(0, 1); CNOT_GATE(1, 2); CNOT_GATE(2, 3);

    // fused RY(w[0,4+q] + w[1,q])
    #pragma unroll
    for (int q = 0; q < 4; ++q) {
        const float c = tw[q], s = tw[4 + q];
        RY_GATE(q, c, s);
    }

    // depth 1 entangler
    CNOT_GATE(0, 1); CNOT_GATE(1, 2); CNOT_GATE(2, 3);

    // RY(w[1,4+q])
    #pragma unroll
    for (int q = 0; q < 4; ++q) {
        const float c = tw[8 + q], s = tw[12 + q];
        RY_GATE(q, c, s);
    }

    // measurement: ev_q = sum_{bit_q=0} psi^2 - sum_{bit_q=1} psi^2
    float sq[16];
    #pragma unroll
    for (int i = 0; i < 16; ++i) sq[i] = psi[i] * psi[i];

    float ev[4];
    #pragma unroll
    for (int q = 0; q < 4; ++q) {
        const int bq = 1 << (3 - q);
        float pos = 0.0f, neg = 0.0f;
        #pragma unroll
        for (int i = 0; i < 16; ++i) {
            if (i & bq) neg += sq[i];
            else        pos += sq[i];
        }
        ev[q] = pos - neg;
    }

    // out[b, p*4 + q] -> flat offset b*784 + p*4 == t*4 (16B aligned)
    float4 o;
    o.x = ev[0]; o.y = ev[1]; o.z = ev[2]; o.w = ev[3];
    *reinterpret_cast<float4*>(out + 4 * t) = o;
}

extern "C" void kernel_launch(void* const* d_in, const int* in_sizes, int n_in,
                              void* d_out, int out_size, void* d_ws, size_t ws_size,
                              hipStream_t stream) {
    const float* x = (const float*)d_in[0];
    const float* w = (const float*)d_in[1];
    float* out = (float*)d_out;
    (void)in_sizes; (void)n_in; (void)d_ws; (void)ws_size; (void)out_size;

    const int total = TOTAL_CIRCUITS;
    const int block = 256;
    const int grid = total / block;   // 3136, exact
    quanv_kernel<<<grid, block, 0, stream>>>(x, w, out);
}